// Round 1
// baseline (497.018 us; speedup 1.0000x reference)
//
#include <hip/hip_runtime.h>
#include <stdint.h>

#define FEAT 128
#define GR   64
#define LDA  136   // 128 + 8 bf16 pad: row pitch 272B = 68 words; lanes i,i+8 alias same bank -> 2-way (free)

typedef __attribute__((ext_vector_type(8))) short bf8_t;
typedef __attribute__((ext_vector_type(4))) float f4_t;

__device__ inline float bf2f(ushort h){
    union { uint u; float f; } v; v.u = ((uint)h) << 16; return v.f;
}
__device__ inline ushort f2bf(float f){
    union { float f; uint u; } v; v.f = f;
    uint r = (v.u + 0x7FFFu + ((v.u >> 16) & 1u)) >> 16;   // RNE
    return (ushort)r;
}

// ---------------- cast x (fp32) -> bf16 ----------------
__global__ void k_cast(const float* __restrict__ x, ushort* __restrict__ xb, int n4){
    int i = blockIdx.x * blockDim.x + threadIdx.x;
    if (i >= n4) return;
    float4 v = ((const float4*)x)[i];
    ushort4 o; o.x = f2bf(v.x); o.y = f2bf(v.y); o.z = f2bf(v.z); o.w = f2bf(v.w);
    ((ushort4*)xb)[i] = o;
}

// ---------------- CSR build ----------------
__global__ void k_count(const int* __restrict__ dst, int* __restrict__ cnt, int E){
    int e = blockIdx.x * blockDim.x + threadIdx.x;
    if (e < E) atomicAdd(&cnt[dst[e]], 1);
}

// block: 256 thr x 4 elems = 1024-elem segment; writes local exclusive scan + block sum
__global__ void k_scan1(const int* __restrict__ cnt, int* __restrict__ rowp,
                        int* __restrict__ bsum, int N){
    __shared__ int sd[256];
    int b = blockIdx.x, t = threadIdx.x;
    int base = b * 1024 + t * 4;
    int v[4], ts = 0;
    #pragma unroll
    for (int i = 0; i < 4; i++){ v[i] = (base + i < N) ? cnt[base + i] : 0; ts += v[i]; }
    sd[t] = ts; __syncthreads();
    for (int off = 1; off < 256; off <<= 1){
        int x = (t >= off) ? sd[t - off] : 0;
        __syncthreads();
        sd[t] += x;
        __syncthreads();
    }
    int run = sd[t] - ts;   // exclusive prefix of this thread within block
    #pragma unroll
    for (int i = 0; i < 4; i++){ if (base + i < N) rowp[base + i] = run; run += v[i]; }
    if (t == 255) bsum[b] = sd[255];
}

__global__ void k_scan2(int* __restrict__ bsum, int* __restrict__ rowp, int NB, int N){
    __shared__ int sd[128];
    int t = threadIdx.x;
    int v = (t < NB) ? bsum[t] : 0;
    sd[t] = v; __syncthreads();
    for (int off = 1; off < 128; off <<= 1){
        int x = (t >= off) ? sd[t - off] : 0;
        __syncthreads();
        sd[t] += x;
        __syncthreads();
    }
    if (t < NB) bsum[t] = sd[t] - v;      // exclusive block offsets
    if (t == 127) rowp[N] = sd[127];      // grand total
}

__global__ void k_scan3(int* __restrict__ rowp, int* __restrict__ cur,
                        const int* __restrict__ bsum, int N){
    int b = blockIdx.x;
    int base = b * 1024 + threadIdx.x * 4;
    int add = bsum[b];
    #pragma unroll
    for (int i = 0; i < 4; i++){
        int idx = base + i;
        if (idx < N){ int v = rowp[idx] + add; rowp[idx] = v; cur[idx] = v; }
    }
}

__global__ void k_fill(const int* __restrict__ src, const int* __restrict__ dst,
                       int* __restrict__ cur, int* __restrict__ csr, int E){
    int e = blockIdx.x * blockDim.x + threadIdx.x;
    if (e < E){
        int p = atomicAdd(&cur[dst[e]], 1);
        csr[p] = src[e];
    }
}

// ---------------- mean aggregation (gather over CSR) ----------------
// 64 lanes per node (2 bf16 feats each), 4 nodes per 256-thr block
__global__ void k_agg(const ushort* __restrict__ srcf, const int* __restrict__ rowp,
                      const int* __restrict__ csr, ushort* __restrict__ aggb, int M){
    int node = blockIdx.x * 4 + (threadIdx.x >> 6);
    int f2 = threadIdx.x & 63;
    if (node >= M) return;
    int s = rowp[node], e = rowp[node + 1];
    float a0 = 0.f, a1 = 0.f;
    for (int i = s; i < e; i++){
        int sn = csr[i];
        uint v = *(const uint*)(srcf + (size_t)sn * FEAT + f2 * 2);
        a0 += bf2f((ushort)(v & 0xffffu));
        a1 += bf2f((ushort)(v >> 16));
    }
    float inv = (e > s) ? 1.0f / (float)(e - s) : 0.f;  // count clamped to 1
    uint o = ((uint)f2bf(a1 * inv) << 16) | (uint)f2bf(a0 * inv);
    *(uint*)(aggb + (size_t)node * FEAT + f2 * 2) = o;
}

// ---------------- fused SAGE linear: H = relu(AGG@Wl^T + b + A@Wr^T) ----------------
// block: 256 thr = 4 waves; tile 64 nodes x 128 out feats; two K=128 passes
__global__ __launch_bounds__(256) void k_gemm(
    const ushort* __restrict__ Aagg, const ushort* __restrict__ Aself,
    const float* __restrict__ Wl, const float* __restrict__ Wr,
    const float* __restrict__ bias, ushort* __restrict__ Hout, int M)
{
    __shared__ ushort As[64 * LDA];
    __shared__ ushort Bs[128 * LDA];
    const int tid  = threadIdx.x;
    const int lane = tid & 63;
    const int wave = tid >> 6;
    const int l15  = lane & 15;
    const int quad = lane >> 4;
    const int m0   = blockIdx.x * 64;

    f4_t acc[8];
    #pragma unroll
    for (int i = 0; i < 8; i++) acc[i] = (f4_t){0.f, 0.f, 0.f, 0.f};

    #pragma unroll
    for (int pass = 0; pass < 2; pass++){
        const ushort* Ap = pass ? Aself : Aagg;
        const float*  Wp = pass ? Wr    : Wl;
        // stage A tile: 64 rows x 128 bf16 (coalesced 16B per thread)
        #pragma unroll
        for (int it = 0; it < 4; it++){
            int idx = (it * 256 + tid) * 8;
            int r = idx >> 7, c = idx & 127;
            int4 v = {0, 0, 0, 0};
            if (m0 + r < M) v = *(const int4*)(Ap + (size_t)(m0 + r) * FEAT + c);
            *(int4*)(&As[r * LDA + c]) = v;
        }
        // stage B = W (row-major [out][k]) fp32 -> bf16
        #pragma unroll
        for (int it = 0; it < 16; it++){
            int idx = (it * 256 + tid) * 4;
            int r = idx >> 7, c = idx & 127;
            float4 wv = *(const float4*)(Wp + idx);
            ushort4 o; o.x = f2bf(wv.x); o.y = f2bf(wv.y); o.z = f2bf(wv.z); o.w = f2bf(wv.w);
            *(ushort4*)(&Bs[r * LDA + c]) = o;
        }
        __syncthreads();
        // A-frag: A[m=lane&15][k=quad*8+j]; B-frag same pattern off row-major [n][k]
        const ushort* arow = &As[(wave * 16 + l15) * LDA + quad * 8];
        const ushort* brow = &Bs[l15 * LDA + quad * 8];
        #pragma unroll
        for (int nt = 0; nt < 8; nt++){
            #pragma unroll
            for (int ks = 0; ks < 4; ks++){
                bf8_t a = *(const bf8_t*)(arow + ks * 32);
                bf8_t b = *(const bf8_t*)(brow + nt * 16 * LDA + ks * 32);
                acc[nt] = __builtin_amdgcn_mfma_f32_16x16x32_bf16(a, b, acc[nt], 0, 0, 0);
            }
        }
        __syncthreads();
    }
    // epilogue: D row = quad*4+reg, col = lane&15
    #pragma unroll
    for (int nt = 0; nt < 8; nt++){
        int col = nt * 16 + l15;
        float bcol = bias[col];
        #pragma unroll
        for (int reg = 0; reg < 4; reg++){
            int gm = m0 + wave * 16 + quad * 4 + reg;
            if (gm < M){
                float v = acc[nt][reg] + bcol;
                v = v > 0.f ? v : 0.f;
                Hout[(size_t)gm * FEAT + col] = f2bf(v);
            }
        }
    }
}

// ---------------- pooling: batch is sorted -> run-length flush ----------------
__global__ void k_pool(const ushort* __restrict__ h, const int* __restrict__ batch,
                       float* __restrict__ pooled, int M){
    int f   = threadIdx.x & 127;
    int sub = threadIdx.x >> 7;
    int n0  = blockIdx.x * 256 + sub * 128;
    if (n0 >= M) return;
    int n1 = min(n0 + 128, M);
    int g = batch[n0];
    float s = 0.f;
    for (int n = n0; n < n1; n++){
        int gn = batch[n];
        if (gn != g){ atomicAdd(&pooled[g * FEAT + f], s); s = 0.f; g = gn; }
        s += bf2f(h[(size_t)n * FEAT + f]);
    }
    atomicAdd(&pooled[g * FEAT + f], s);
}

// ---------------- final linear over [pooled/cnt | embed] ----------------
__global__ void k_final(const float* __restrict__ pooled, const int* __restrict__ batch,
                        const float* __restrict__ embed, const float* __restrict__ Wlin,
                        const float* __restrict__ blin, float* __restrict__ out, int M){
    int t = threadIdx.x;
    if (t >= GR * 8) return;
    int g = t >> 3, o = t & 7;
    // node count for graph g via binary search on sorted batch
    int lo = 0, hi = M;
    while (lo < hi){ int mid = (lo + hi) >> 1; if (batch[mid] < g) lo = mid + 1; else hi = mid; }
    int s0 = lo;
    lo = s0; hi = M;
    while (lo < hi){ int mid = (lo + hi) >> 1; if (batch[mid] < g + 1) lo = mid + 1; else hi = mid; }
    int c = lo - s0;
    float inv = (c > 0) ? 1.0f / (float)c : 0.f;
    float acc = blin[o];
    const float* wr = Wlin + o * (FEAT + GR);
    for (int k = 0; k < FEAT; k++) acc += pooled[g * FEAT + k] * inv * wr[k];
    for (int k = 0; k < GR; k++)   acc += embed[g * GR + k] * wr[FEAT + k];
    out[g * 8 + o] = acc;
}

extern "C" void kernel_launch(void* const* d_in, const int* in_sizes, int n_in,
                              void* d_out, int out_size, void* d_ws, size_t ws_size,
                              hipStream_t stream)
{
    const float* x     = (const float*)d_in[0];
    const int*   eidx  = (const int*)d_in[1];
    const int*   batch = (const int*)d_in[2];
    const float* embed = (const float*)d_in[3];
    const float* W1l   = (const float*)d_in[4];
    const float* b1l   = (const float*)d_in[5];
    const float* W1r   = (const float*)d_in[6];
    const float* W2l   = (const float*)d_in[7];
    const float* b2l   = (const float*)d_in[8];
    const float* W2r   = (const float*)d_in[9];
    const float* Wlin  = (const float*)d_in[10];
    const float* blin  = (const float*)d_in[11];
    float* out = (float*)d_out;

    const int M = in_sizes[0] / FEAT;   // 100000
    const int E = in_sizes[1] / 2;      // 800000
    const int* src = eidx;
    const int* dst = eidx + E;

    char* w = (char*)d_ws;
    size_t off = 0;
    auto alloc = [&](size_t sz){ void* p = w + off; off = (off + sz + 255) & ~(size_t)255; return p; };
    ushort* xb     = (ushort*)alloc((size_t)M * FEAT * 2);
    ushort* aggb   = (ushort*)alloc((size_t)M * FEAT * 2);
    ushort* h1b    = (ushort*)alloc((size_t)M * FEAT * 2);
    int*    cnt    = (int*)alloc((size_t)M * 4);
    int*    rowp   = (int*)alloc((size_t)(M + 1) * 4);
    int*    cur    = (int*)alloc((size_t)M * 4);
    int*    bsum   = (int*)alloc(512);
    int*    csr    = (int*)alloc((size_t)E * 4);
    float*  pooled = (float*)alloc((size_t)GR * FEAT * 4);
    ushort* h2b = xb;  // xb dead after layer-1 GEMM; reuse for h2

    hipMemsetAsync(cnt, 0, (size_t)M * 4, stream);
    hipMemsetAsync(pooled, 0, (size_t)GR * FEAT * 4, stream);

    int NB = (M + 1023) / 1024;
    k_cast <<<(M * FEAT / 4 + 255) / 256, 256, 0, stream>>>(x, xb, M * FEAT / 4);
    k_count<<<(E + 255) / 256, 256, 0, stream>>>(dst, cnt, E);
    k_scan1<<<NB, 256, 0, stream>>>(cnt, rowp, bsum, M);
    k_scan2<<<1, 128, 0, stream>>>(bsum, rowp, NB, M);
    k_scan3<<<NB, 256, 0, stream>>>(rowp, cur, bsum, M);
    k_fill <<<(E + 255) / 256, 256, 0, stream>>>(src, dst, cur, csr, E);
    k_agg  <<<(M + 3) / 4, 256, 0, stream>>>(xb, rowp, csr, aggb, M);
    k_gemm <<<(M + 63) / 64, 256, 0, stream>>>(aggb, xb, W1l, W1r, b1l, h1b, M);
    k_agg  <<<(M + 3) / 4, 256, 0, stream>>>(h1b, rowp, csr, aggb, M);
    k_gemm <<<(M + 63) / 64, 256, 0, stream>>>(aggb, h1b, W2l, W2r, b2l, h2b, M);
    k_pool <<<(M + 255) / 256, 256, 0, stream>>>(h2b, batch, pooled, M);
    k_final<<<1, 512, 0, stream>>>(pooled, batch, embed, Wlin, blin, out, M);
}

// Round 2
// 422.271 us; speedup vs baseline: 1.1770x; 1.1770x over previous
//
#include <hip/hip_runtime.h>
#include <stdint.h>

#define FEAT 128
#define GR   64
#define LDA  136   // 128 + 8 bf16 pad: row pitch 272B = 68 words; 2-way bank alias only (free)

typedef __attribute__((ext_vector_type(8))) short bf8_t;
typedef __attribute__((ext_vector_type(4))) float f4_t;

__device__ inline float bf2f(ushort h){
    union { uint u; float f; } v; v.u = ((uint)h) << 16; return v.f;
}
__device__ inline ushort f2bf(float f){
    union { float f; uint u; } v; v.f = f;
    uint r = (v.u + 0x7FFFu + ((v.u >> 16) & 1u)) >> 16;   // RNE
    return (ushort)r;
}

// ---------------- cast fp32 -> bf16 (x and weights) ----------------
__global__ void k_cast(const float* __restrict__ x, ushort* __restrict__ xb, int n4){
    int i = blockIdx.x * blockDim.x + threadIdx.x;
    if (i >= n4) return;
    float4 v = ((const float4*)x)[i];
    ushort4 o; o.x = f2bf(v.x); o.y = f2bf(v.y); o.z = f2bf(v.z); o.w = f2bf(v.w);
    ((ushort4*)xb)[i] = o;
}

// ---------------- CSR build ----------------
__global__ void k_count(const int* __restrict__ dst, int* __restrict__ cnt, int E){
    int e = blockIdx.x * blockDim.x + threadIdx.x;
    if (e < E) atomicAdd(&cnt[dst[e]], 1);
}

__global__ void k_scan1(const int* __restrict__ cnt, int* __restrict__ rowp,
                        int* __restrict__ bsum, int N){
    __shared__ int sd[256];
    int b = blockIdx.x, t = threadIdx.x;
    int base = b * 1024 + t * 4;
    int v[4], ts = 0;
    #pragma unroll
    for (int i = 0; i < 4; i++){ v[i] = (base + i < N) ? cnt[base + i] : 0; ts += v[i]; }
    sd[t] = ts; __syncthreads();
    for (int off = 1; off < 256; off <<= 1){
        int x = (t >= off) ? sd[t - off] : 0;
        __syncthreads();
        sd[t] += x;
        __syncthreads();
    }
    int run = sd[t] - ts;
    #pragma unroll
    for (int i = 0; i < 4; i++){ if (base + i < N) rowp[base + i] = run; run += v[i]; }
    if (t == 255) bsum[b] = sd[255];
}

__global__ void k_scan2(int* __restrict__ bsum, int* __restrict__ rowp, int NB, int N){
    __shared__ int sd[128];
    int t = threadIdx.x;
    int v = (t < NB) ? bsum[t] : 0;
    sd[t] = v; __syncthreads();
    for (int off = 1; off < 128; off <<= 1){
        int x = (t >= off) ? sd[t - off] : 0;
        __syncthreads();
        sd[t] += x;
        __syncthreads();
    }
    if (t < NB) bsum[t] = sd[t] - v;
    if (t == 127) rowp[N] = sd[127];
}

__global__ void k_scan3(int* __restrict__ rowp, int* __restrict__ cur,
                        const int* __restrict__ bsum, int N){
    int b = blockIdx.x;
    int base = b * 1024 + threadIdx.x * 4;
    int add = bsum[b];
    #pragma unroll
    for (int i = 0; i < 4; i++){
        int idx = base + i;
        if (idx < N){ int v = rowp[idx] + add; rowp[idx] = v; cur[idx] = v; }
    }
}

__global__ void k_fill(const int* __restrict__ src, const int* __restrict__ dst,
                       int* __restrict__ cur, int* __restrict__ csr, int E){
    int e = blockIdx.x * blockDim.x + threadIdx.x;
    if (e < E){
        int p = atomicAdd(&cur[dst[e]], 1);
        csr[p] = src[e];
    }
}

// ---------------- mean aggregation (gather over CSR), 4-deep MLP unroll ----------------
// 64 lanes per node (2 bf16 feats each), 4 nodes per 256-thr block
__global__ void k_agg(const ushort* __restrict__ srcf, const int* __restrict__ rowp,
                      const int* __restrict__ csr, ushort* __restrict__ aggb, int M){
    int node = blockIdx.x * 4 + (threadIdx.x >> 6);
    int f2 = threadIdx.x & 63;
    if (node >= M) return;
    int s = rowp[node], e = rowp[node + 1];
    float a0 = 0.f, a1 = 0.f, b0 = 0.f, b1 = 0.f;
    float c0 = 0.f, c1 = 0.f, d0 = 0.f, d1 = 0.f;
    int i = s;
    for (; i + 4 <= e; i += 4){
        int sn0 = csr[i], sn1 = csr[i + 1], sn2 = csr[i + 2], sn3 = csr[i + 3];
        uint v0 = *(const uint*)(srcf + (size_t)sn0 * FEAT + f2 * 2);
        uint v1 = *(const uint*)(srcf + (size_t)sn1 * FEAT + f2 * 2);
        uint v2 = *(const uint*)(srcf + (size_t)sn2 * FEAT + f2 * 2);
        uint v3 = *(const uint*)(srcf + (size_t)sn3 * FEAT + f2 * 2);
        a0 += bf2f((ushort)(v0 & 0xffffu)); a1 += bf2f((ushort)(v0 >> 16));
        b0 += bf2f((ushort)(v1 & 0xffffu)); b1 += bf2f((ushort)(v1 >> 16));
        c0 += bf2f((ushort)(v2 & 0xffffu)); c1 += bf2f((ushort)(v2 >> 16));
        d0 += bf2f((ushort)(v3 & 0xffffu)); d1 += bf2f((ushort)(v3 >> 16));
    }
    for (; i < e; i++){
        int sn = csr[i];
        uint v = *(const uint*)(srcf + (size_t)sn * FEAT + f2 * 2);
        a0 += bf2f((ushort)(v & 0xffffu)); a1 += bf2f((ushort)(v >> 16));
    }
    float s0 = (a0 + b0) + (c0 + d0);
    float s1 = (a1 + b1) + (c1 + d1);
    float inv = (e > s) ? 1.0f / (float)(e - s) : 0.f;  // count clamped to 1
    uint o = ((uint)f2bf(s1 * inv) << 16) | (uint)f2bf(s0 * inv);
    *(uint*)(aggb + (size_t)node * FEAT + f2 * 2) = o;
}

// ---------------- fused SAGE linear: H = relu(AGG@Wl^T + b + A@Wr^T) ----------------
// block: 256 thr = 4 waves; tile 64 nodes x 128 out feats; two K=128 passes; bf16 weights
__global__ __launch_bounds__(256) void k_gemm(
    const ushort* __restrict__ Aagg, const ushort* __restrict__ Aself,
    const ushort* __restrict__ Wl, const ushort* __restrict__ Wr,
    const float* __restrict__ bias, ushort* __restrict__ Hout, int M)
{
    __shared__ ushort As[64 * LDA];
    __shared__ ushort Bs[128 * LDA];
    const int tid  = threadIdx.x;
    const int lane = tid & 63;
    const int wave = tid >> 6;
    const int l15  = lane & 15;
    const int quad = lane >> 4;
    const int m0   = blockIdx.x * 64;

    f4_t acc[8];
    #pragma unroll
    for (int i = 0; i < 8; i++) acc[i] = (f4_t){0.f, 0.f, 0.f, 0.f};

    #pragma unroll
    for (int pass = 0; pass < 2; pass++){
        const ushort* Ap = pass ? Aself : Aagg;
        const ushort* Wp = pass ? Wr    : Wl;
        // stage A tile: 64 rows x 128 bf16 (16B per thread)
        #pragma unroll
        for (int it = 0; it < 4; it++){
            int idx = (it * 256 + tid) * 8;
            int r = idx >> 7, c = idx & 127;
            int4 v = {0, 0, 0, 0};
            if (m0 + r < M) v = *(const int4*)(Ap + (size_t)(m0 + r) * FEAT + c);
            *(int4*)(&As[r * LDA + c]) = v;
        }
        // stage B = W (row-major [out][k], already bf16): 16B per thread
        #pragma unroll
        for (int it = 0; it < 8; it++){
            int idx = (it * 256 + tid) * 8;
            int r = idx >> 7, c = idx & 127;
            *(int4*)(&Bs[r * LDA + c]) = *(const int4*)(Wp + idx);
        }
        __syncthreads();
        // A-frag: A[m=lane&15][k=quad*8+j]; B-frag same pattern off row-major [n][k]
        const ushort* arow = &As[(wave * 16 + l15) * LDA + quad * 8];
        const ushort* brow = &Bs[l15 * LDA + quad * 8];
        #pragma unroll
        for (int nt = 0; nt < 8; nt++){
            #pragma unroll
            for (int ks = 0; ks < 4; ks++){
                bf8_t a = *(const bf8_t*)(arow + ks * 32);
                bf8_t b = *(const bf8_t*)(brow + nt * 16 * LDA + ks * 32);
                acc[nt] = __builtin_amdgcn_mfma_f32_16x16x32_bf16(a, b, acc[nt], 0, 0, 0);
            }
        }
        __syncthreads();
    }
    // epilogue: D row = quad*4+reg, col = lane&15
    #pragma unroll
    for (int nt = 0; nt < 8; nt++){
        int col = nt * 16 + l15;
        float bcol = bias[col];
        #pragma unroll
        for (int reg = 0; reg < 4; reg++){
            int gm = m0 + wave * 16 + quad * 4 + reg;
            if (gm < M){
                float v = acc[nt][reg] + bcol;
                v = v > 0.f ? v : 0.f;
                Hout[(size_t)gm * FEAT + col] = f2bf(v);
            }
        }
    }
}

// ---------------- pooling: batch is sorted -> run-length flush ----------------
__global__ void k_pool(const ushort* __restrict__ h, const int* __restrict__ batch,
                       float* __restrict__ pooled, int M){
    int f   = threadIdx.x & 127;
    int sub = threadIdx.x >> 7;
    int n0  = blockIdx.x * 256 + sub * 128;
    if (n0 >= M) return;
    int n1 = min(n0 + 128, M);
    int g = batch[n0];
    float s = 0.f;
    for (int n = n0; n < n1; n++){
        int gn = batch[n];
        if (gn != g){ atomicAdd(&pooled[g * FEAT + f], s); s = 0.f; g = gn; }
        s += bf2f(h[(size_t)n * FEAT + f]);
    }
    atomicAdd(&pooled[g * FEAT + f], s);
}

// ---------------- final linear over [pooled/cnt | embed] ----------------
__global__ void k_final(const float* __restrict__ pooled, const int* __restrict__ batch,
                        const float* __restrict__ embed, const float* __restrict__ Wlin,
                        const float* __restrict__ blin, float* __restrict__ out, int M){
    int t = threadIdx.x;
    if (t >= GR * 8) return;
    int g = t >> 3, o = t & 7;
    int lo = 0, hi = M;
    while (lo < hi){ int mid = (lo + hi) >> 1; if (batch[mid] < g) lo = mid + 1; else hi = mid; }
    int s0 = lo;
    lo = s0; hi = M;
    while (lo < hi){ int mid = (lo + hi) >> 1; if (batch[mid] < g + 1) lo = mid + 1; else hi = mid; }
    int c = lo - s0;
    float inv = (c > 0) ? 1.0f / (float)c : 0.f;
    float acc = blin[o];
    const float* wr = Wlin + o * (FEAT + GR);
    for (int k = 0; k < FEAT; k++) acc += pooled[g * FEAT + k] * inv * wr[k];
    for (int k = 0; k < GR; k++)   acc += embed[g * GR + k] * wr[FEAT + k];
    out[g * 8 + o] = acc;
}

extern "C" void kernel_launch(void* const* d_in, const int* in_sizes, int n_in,
                              void* d_out, int out_size, void* d_ws, size_t ws_size,
                              hipStream_t stream)
{
    const float* x     = (const float*)d_in[0];
    const int*   eidx  = (const int*)d_in[1];
    const int*   batch = (const int*)d_in[2];
    const float* embed = (const float*)d_in[3];
    const float* W1l   = (const float*)d_in[4];
    const float* b1l   = (const float*)d_in[5];
    const float* W1r   = (const float*)d_in[6];
    const float* W2l   = (const float*)d_in[7];
    const float* b2l   = (const float*)d_in[8];
    const float* W2r   = (const float*)d_in[9];
    const float* Wlin  = (const float*)d_in[10];
    const float* blin  = (const float*)d_in[11];
    float* out = (float*)d_out;

    const int M = in_sizes[0] / FEAT;   // 100000
    const int E = in_sizes[1] / 2;      // 800000
    const int* src = eidx;
    const int* dst = eidx + E;

    char* w = (char*)d_ws;
    size_t off = 0;
    auto alloc = [&](size_t sz){ void* p = w + off; off = (off + sz + 255) & ~(size_t)255; return p; };
    ushort* xb     = (ushort*)alloc((size_t)M * FEAT * 2);
    ushort* aggb   = (ushort*)alloc((size_t)M * FEAT * 2);
    ushort* h1b    = (ushort*)alloc((size_t)M * FEAT * 2);
    int*    cnt    = (int*)alloc((size_t)M * 4);
    int*    rowp   = (int*)alloc((size_t)(M + 1) * 4);
    int*    cur    = (int*)alloc((size_t)M * 4);
    int*    bsum   = (int*)alloc(512);
    int*    csr    = (int*)alloc((size_t)E * 4);
    float*  pooled = (float*)alloc((size_t)GR * FEAT * 4);
    ushort* w1lb   = (ushort*)alloc((size_t)FEAT * FEAT * 2);
    ushort* w1rb   = (ushort*)alloc((size_t)FEAT * FEAT * 2);
    ushort* w2lb   = (ushort*)alloc((size_t)FEAT * FEAT * 2);
    ushort* w2rb   = (ushort*)alloc((size_t)FEAT * FEAT * 2);
    ushort* h2b = xb;  // xb dead after layer-1 GEMM; reuse for h2

    hipMemsetAsync(cnt, 0, (size_t)M * 4, stream);
    hipMemsetAsync(pooled, 0, (size_t)GR * FEAT * 4, stream);

    int NB = (M + 1023) / 1024;
    const int WN4 = FEAT * FEAT / 4;  // 4096
    k_cast <<<(M * FEAT / 4 + 255) / 256, 256, 0, stream>>>(x, xb, M * FEAT / 4);
    k_cast <<<(WN4 + 255) / 256, 256, 0, stream>>>(W1l, w1lb, WN4);
    k_cast <<<(WN4 + 255) / 256, 256, 0, stream>>>(W1r, w1rb, WN4);
    k_cast <<<(WN4 + 255) / 256, 256, 0, stream>>>(W2l, w2lb, WN4);
    k_cast <<<(WN4 + 255) / 256, 256, 0, stream>>>(W2r, w2rb, WN4);
    k_count<<<(E + 255) / 256, 256, 0, stream>>>(dst, cnt, E);
    k_scan1<<<NB, 256, 0, stream>>>(cnt, rowp, bsum, M);
    k_scan2<<<1, 128, 0, stream>>>(bsum, rowp, NB, M);
    k_scan3<<<NB, 256, 0, stream>>>(rowp, cur, bsum, M);
    k_fill <<<(E + 255) / 256, 256, 0, stream>>>(src, dst, cur, csr, E);
    k_agg  <<<(M + 3) / 4, 256, 0, stream>>>(xb, rowp, csr, aggb, M);
    k_gemm <<<(M + 63) / 64, 256, 0, stream>>>(aggb, xb, w1lb, w1rb, b1l, h1b, M);
    k_agg  <<<(M + 3) / 4, 256, 0, stream>>>(h1b, rowp, csr, aggb, M);
    k_gemm <<<(M + 63) / 64, 256, 0, stream>>>(aggb, h1b, w2lb, w2rb, b2l, h2b, M);
    k_pool <<<(M + 255) / 256, 256, 0, stream>>>(h2b, batch, pooled, M);
    k_final<<<1, 512, 0, stream>>>(pooled, batch, embed, Wlin, blin, out, M);
}

// Round 4
// 385.746 us; speedup vs baseline: 1.2885x; 1.0947x over previous
//
#include <hip/hip_runtime.h>
#include <stdint.h>

#define FEAT 128
#define GR   64
#define LDA  136   // 128 + 8 bf16 pad: row pitch 272B; 2-way bank alias only (free)

typedef __attribute__((ext_vector_type(8))) short bf8_t;
typedef __attribute__((ext_vector_type(4))) float f4_t;

__device__ inline float bf2f(ushort h){
    union { uint u; float f; } v; v.u = ((uint)h) << 16; return v.f;
}
__device__ inline ushort f2bf(float f){
    union { float f; uint u; } v; v.f = f;
    uint r = (v.u + 0x7FFFu + ((v.u >> 16) & 1u)) >> 16;   // RNE
    return (ushort)r;
}

// ---------------- cast fp32 -> bf16 (node features) ----------------
__global__ void k_cast(const float* __restrict__ x, ushort* __restrict__ xb, int n4){
    int i = blockIdx.x * blockDim.x + threadIdx.x;
    if (i >= n4) return;
    float4 v = ((const float4*)x)[i];
    ushort4 o; o.x = f2bf(v.x); o.y = f2bf(v.y); o.z = f2bf(v.z); o.w = f2bf(v.w);
    ((ushort4*)xb)[i] = o;
}

// cast all four 128x128 weight matrices in one launch
__global__ void k_castw(const float* __restrict__ a0, const float* __restrict__ a1,
                        const float* __restrict__ a2, const float* __restrict__ a3,
                        ushort* __restrict__ o0, ushort* __restrict__ o1,
                        ushort* __restrict__ o2, ushort* __restrict__ o3){
    int i = blockIdx.x * blockDim.x + threadIdx.x;   // 0..16383 float4s
    int sel = i >> 12, j = i & 4095;
    const float* s = sel == 0 ? a0 : sel == 1 ? a1 : sel == 2 ? a2 : a3;
    ushort*      d = sel == 0 ? o0 : sel == 1 ? o1 : sel == 2 ? o2 : o3;
    float4 v = ((const float4*)s)[j];
    ushort4 o; o.x = f2bf(v.x); o.y = f2bf(v.y); o.z = f2bf(v.z); o.w = f2bf(v.w);
    ((ushort4*)d)[j] = o;
}

// ---------------- CSR build ----------------
__global__ void k_count(const int* __restrict__ dst, int* __restrict__ cnt, int E){
    int e = blockIdx.x * blockDim.x + threadIdx.x;
    if (e < E) atomicAdd(&cnt[dst[e]], 1);
}

__global__ void k_scan1(const int* __restrict__ cnt, int* __restrict__ rowp,
                        int* __restrict__ bsum, int N){
    __shared__ int sd[256];
    int b = blockIdx.x, t = threadIdx.x;
    int base = b * 1024 + t * 4;
    int v[4], ts = 0;
    #pragma unroll
    for (int i = 0; i < 4; i++){ v[i] = (base + i < N) ? cnt[base + i] : 0; ts += v[i]; }
    sd[t] = ts; __syncthreads();
    for (int off = 1; off < 256; off <<= 1){
        int x = (t >= off) ? sd[t - off] : 0;
        __syncthreads();
        sd[t] += x;
        __syncthreads();
    }
    int run = sd[t] - ts;
    #pragma unroll
    for (int i = 0; i < 4; i++){ if (base + i < N) rowp[base + i] = run; run += v[i]; }
    if (t == 255) bsum[b] = sd[255];
}

__global__ void k_scan2(int* __restrict__ bsum, int* __restrict__ rowp, int NB, int N){
    __shared__ int sd[128];
    int t = threadIdx.x;
    int v = (t < NB) ? bsum[t] : 0;
    sd[t] = v; __syncthreads();
    for (int off = 1; off < 128; off <<= 1){
        int x = (t >= off) ? sd[t - off] : 0;
        __syncthreads();
        sd[t] += x;
        __syncthreads();
    }
    if (t < NB) bsum[t] = sd[t] - v;
    if (t == 127) rowp[N] = sd[127];
}

__global__ void k_scan3(int* __restrict__ rowp, int* __restrict__ cur,
                        const int* __restrict__ bsum, int N){
    int b = blockIdx.x;
    int base = b * 1024 + threadIdx.x * 4;
    int add = bsum[b];
    #pragma unroll
    for (int i = 0; i < 4; i++){
        int idx = base + i;
        if (idx < N){ int v = rowp[idx] + add; rowp[idx] = v; cur[idx] = v; }
    }
}

__global__ void k_fill(const int* __restrict__ src, const int* __restrict__ dst,
                       int* __restrict__ cur, int* __restrict__ csr, int E){
    int e = blockIdx.x * blockDim.x + threadIdx.x;
    if (e < E){
        int p = atomicAdd(&cur[dst[e]], 1);
        csr[p] = src[e];
    }
}

// ---------------- mean aggregation (gather over CSR), 8-deep MLP unroll ----------------
// 64 lanes per node (2 bf16 feats each), 4 nodes per 256-thr block
__global__ void k_agg(const ushort* __restrict__ srcf, const int* __restrict__ rowp,
                      const int* __restrict__ csr, ushort* __restrict__ aggb, int M){
    int node = blockIdx.x * 4 + (threadIdx.x >> 6);
    int f2 = threadIdx.x & 63;
    if (node >= M) return;
    int s = rowp[node], e = rowp[node + 1];
    float a0 = 0.f, a1 = 0.f, b0 = 0.f, b1 = 0.f;
    float c0 = 0.f, c1 = 0.f, d0 = 0.f, d1 = 0.f;
    float e0 = 0.f, e1 = 0.f, g0 = 0.f, g1 = 0.f;
    float p0 = 0.f, p1 = 0.f, q0 = 0.f, q1 = 0.f;
    int i = s;
    for (; i + 8 <= e; i += 8){
        int sn0 = csr[i],     sn1 = csr[i + 1], sn2 = csr[i + 2], sn3 = csr[i + 3];
        int sn4 = csr[i + 4], sn5 = csr[i + 5], sn6 = csr[i + 6], sn7 = csr[i + 7];
        uint v0 = *(const uint*)(srcf + (size_t)sn0 * FEAT + f2 * 2);
        uint v1 = *(const uint*)(srcf + (size_t)sn1 * FEAT + f2 * 2);
        uint v2 = *(const uint*)(srcf + (size_t)sn2 * FEAT + f2 * 2);
        uint v3 = *(const uint*)(srcf + (size_t)sn3 * FEAT + f2 * 2);
        uint v4 = *(const uint*)(srcf + (size_t)sn4 * FEAT + f2 * 2);
        uint v5 = *(const uint*)(srcf + (size_t)sn5 * FEAT + f2 * 2);
        uint v6 = *(const uint*)(srcf + (size_t)sn6 * FEAT + f2 * 2);
        uint v7 = *(const uint*)(srcf + (size_t)sn7 * FEAT + f2 * 2);
        a0 += bf2f((ushort)(v0 & 0xffffu)); a1 += bf2f((ushort)(v0 >> 16));
        b0 += bf2f((ushort)(v1 & 0xffffu)); b1 += bf2f((ushort)(v1 >> 16));
        c0 += bf2f((ushort)(v2 & 0xffffu)); c1 += bf2f((ushort)(v2 >> 16));
        d0 += bf2f((ushort)(v3 & 0xffffu)); d1 += bf2f((ushort)(v3 >> 16));
        e0 += bf2f((ushort)(v4 & 0xffffu)); e1 += bf2f((ushort)(v4 >> 16));
        g0 += bf2f((ushort)(v5 & 0xffffu)); g1 += bf2f((ushort)(v5 >> 16));
        p0 += bf2f((ushort)(v6 & 0xffffu)); p1 += bf2f((ushort)(v6 >> 16));
        q0 += bf2f((ushort)(v7 & 0xffffu)); q1 += bf2f((ushort)(v7 >> 16));
    }
    for (; i + 2 <= e; i += 2){
        int sn0 = csr[i], sn1 = csr[i + 1];
        uint v0 = *(const uint*)(srcf + (size_t)sn0 * FEAT + f2 * 2);
        uint v1 = *(const uint*)(srcf + (size_t)sn1 * FEAT + f2 * 2);
        a0 += bf2f((ushort)(v0 & 0xffffu)); a1 += bf2f((ushort)(v0 >> 16));
        b0 += bf2f((ushort)(v1 & 0xffffu)); b1 += bf2f((ushort)(v1 >> 16));
    }
    if (i < e){
        int sn = csr[i];
        uint v = *(const uint*)(srcf + (size_t)sn * FEAT + f2 * 2);
        a0 += bf2f((ushort)(v & 0xffffu)); a1 += bf2f((ushort)(v >> 16));
    }
    float s0 = ((a0 + b0) + (c0 + d0)) + ((e0 + g0) + (p0 + q0));
    float s1 = ((a1 + b1) + (c1 + d1)) + ((e1 + g1) + (p1 + q1));
    float inv = (e > s) ? 1.0f / (float)(e - s) : 0.f;  // count clamped to 1
    uint o = ((uint)f2bf(s1 * inv) << 16) | (uint)f2bf(s0 * inv);
    *(uint*)(aggb + (size_t)node * FEAT + f2 * 2) = o;
}

// ---------------- fused SAGE linear: H = relu(AGG@Wl^T + b + A@Wr^T) ----------------
__global__ __launch_bounds__(256) void k_gemm(
    const ushort* __restrict__ Aagg, const ushort* __restrict__ Aself,
    const ushort* __restrict__ Wl, const ushort* __restrict__ Wr,
    const float* __restrict__ bias, ushort* __restrict__ Hout, int M)
{
    __shared__ ushort As[64 * LDA];
    __shared__ ushort Bs[128 * LDA];
    const int tid  = threadIdx.x;
    const int lane = tid & 63;
    const int wave = tid >> 6;
    const int l15  = lane & 15;
    const int quad = lane >> 4;
    const int m0   = blockIdx.x * 64;

    f4_t acc[8];
    #pragma unroll
    for (int i = 0; i < 8; i++) acc[i] = (f4_t){0.f, 0.f, 0.f, 0.f};

    #pragma unroll
    for (int pass = 0; pass < 2; pass++){
        const ushort* Ap = pass ? Aself : Aagg;
        const ushort* Wp = pass ? Wr    : Wl;
        #pragma unroll
        for (int it = 0; it < 4; it++){
            int idx = (it * 256 + tid) * 8;
            int r = idx >> 7, c = idx & 127;
            int4 v = {0, 0, 0, 0};
            if (m0 + r < M) v = *(const int4*)(Ap + (size_t)(m0 + r) * FEAT + c);
            *(int4*)(&As[r * LDA + c]) = v;
        }
        #pragma unroll
        for (int it = 0; it < 8; it++){
            int idx = (it * 256 + tid) * 8;
            int r = idx >> 7, c = idx & 127;
            *(int4*)(&Bs[r * LDA + c]) = *(const int4*)(Wp + idx);
        }
        __syncthreads();
        const ushort* arow = &As[(wave * 16 + l15) * LDA + quad * 8];
        const ushort* brow = &Bs[l15 * LDA + quad * 8];
        #pragma unroll
        for (int nt = 0; nt < 8; nt++){
            #pragma unroll
            for (int ks = 0; ks < 4; ks++){
                bf8_t a = *(const bf8_t*)(arow + ks * 32);
                bf8_t b = *(const bf8_t*)(brow + nt * 16 * LDA + ks * 32);
                acc[nt] = __builtin_amdgcn_mfma_f32_16x16x32_bf16(a, b, acc[nt], 0, 0, 0);
            }
        }
        __syncthreads();
    }
    #pragma unroll
    for (int nt = 0; nt < 8; nt++){
        int col = nt * 16 + l15;
        float bcol = bias[col];
        #pragma unroll
        for (int reg = 0; reg < 4; reg++){
            int gm = m0 + wave * 16 + quad * 4 + reg;
            if (gm < M){
                float v = acc[nt][reg] + bcol;
                v = v > 0.f ? v : 0.f;
                Hout[(size_t)gm * FEAT + col] = f2bf(v);
            }
        }
    }
}

// ---------------- pooling: sorted batch; 16 nodes/thread, 4-wide unroll ----------------
// each 256-thr block = 2 sub-groups x 128 feats; covers 32 nodes -> grid (M+31)/32
__global__ void k_pool(const ushort* __restrict__ h, const int* __restrict__ batch,
                       float* __restrict__ pooled, int M){
    int f   = threadIdx.x & 127;
    int sub = threadIdx.x >> 7;
    int n0  = (blockIdx.x * 2 + sub) * 16;
    if (n0 >= M) return;
    int n1 = min(n0 + 16, M);
    int g = batch[n0];
    float s = 0.f;
    int n = n0;
    for (; n + 4 <= n1; n += 4){
        int g0 = batch[n], g1 = batch[n + 1], g2 = batch[n + 2], g3 = batch[n + 3];
        float v0 = bf2f(h[(size_t)n * FEAT + f]);
        float v1 = bf2f(h[(size_t)(n + 1) * FEAT + f]);
        float v2 = bf2f(h[(size_t)(n + 2) * FEAT + f]);
        float v3 = bf2f(h[(size_t)(n + 3) * FEAT + f]);
        if (g0 != g){ atomicAdd(&pooled[g * FEAT + f], s); s = 0.f; g = g0; } s += v0;
        if (g1 != g){ atomicAdd(&pooled[g * FEAT + f], s); s = 0.f; g = g1; } s += v1;
        if (g2 != g){ atomicAdd(&pooled[g * FEAT + f], s); s = 0.f; g = g2; } s += v2;
        if (g3 != g){ atomicAdd(&pooled[g * FEAT + f], s); s = 0.f; g = g3; } s += v3;
    }
    for (; n < n1; n++){
        int gn = batch[n];
        if (gn != g){ atomicAdd(&pooled[g * FEAT + f], s); s = 0.f; g = gn; }
        s += bf2f(h[(size_t)n * FEAT + f]);
    }
    atomicAdd(&pooled[g * FEAT + f], s);
}

// ---------------- final linear over [pooled/cnt | embed] ----------------
__global__ void k_final(const float* __restrict__ pooled, const int* __restrict__ batch,
                        const float* __restrict__ embed, const float* __restrict__ Wlin,
                        const float* __restrict__ blin, float* __restrict__ out, int M){
    int t = threadIdx.x;
    if (t >= GR * 8) return;
    int g = t >> 3, o = t & 7;
    int lo = 0, hi = M;
    while (lo < hi){ int mid = (lo + hi) >> 1; if (batch[mid] < g) lo = mid + 1; else hi = mid; }
    int s0 = lo;
    lo = s0; hi = M;
    while (lo < hi){ int mid = (lo + hi) >> 1; if (batch[mid] < g + 1) lo = mid + 1; else hi = mid; }
    int c = lo - s0;
    float inv = (c > 0) ? 1.0f / (float)c : 0.f;
    float acc = blin[o];
    const float* wr = Wlin + o * (FEAT + GR);
    for (int k = 0; k < FEAT; k++) acc += pooled[g * FEAT + k] * inv * wr[k];
    for (int k = 0; k < GR; k++)   acc += embed[g * GR + k] * wr[FEAT + k];
    out[g * 8 + o] = acc;
}

extern "C" void kernel_launch(void* const* d_in, const int* in_sizes, int n_in,
                              void* d_out, int out_size, void* d_ws, size_t ws_size,
                              hipStream_t stream)
{
    const float* x     = (const float*)d_in[0];
    const int*   eidx  = (const int*)d_in[1];
    const int*   batch = (const int*)d_in[2];
    const float* embed = (const float*)d_in[3];
    const float* W1l   = (const float*)d_in[4];
    const float* b1l   = (const float*)d_in[5];
    const float* W1r   = (const float*)d_in[6];
    const float* W2l   = (const float*)d_in[7];
    const float* b2l   = (const float*)d_in[8];
    const float* W2r   = (const float*)d_in[9];
    const float* Wlin  = (const float*)d_in[10];
    const float* blin  = (const float*)d_in[11];
    float* out = (float*)d_out;

    const int M = in_sizes[0] / FEAT;   // 100000
    const int E = in_sizes[1] / 2;      // 800000
    const int* src = eidx;
    const int* dst = eidx + E;

    char* w = (char*)d_ws;
    size_t off = 0;
    auto alloc = [&](size_t sz){ void* p = w + off; off = (off + sz + 255) & ~(size_t)255; return p; };
    ushort* xb     = (ushort*)alloc((size_t)M * FEAT * 2);
    ushort* aggb   = (ushort*)alloc((size_t)M * FEAT * 2);
    ushort* h1b    = (ushort*)alloc((size_t)M * FEAT * 2);
    int*    cnt    = (int*)alloc((size_t)M * 4);
    int*    rowp   = (int*)alloc((size_t)(M + 1) * 4);
    int*    cur    = (int*)alloc((size_t)M * 4);
    int*    bsum   = (int*)alloc(512);
    int*    csr    = (int*)alloc((size_t)E * 4);
    float*  pooled = (float*)alloc((size_t)GR * FEAT * 4);
    ushort* w1lb   = (ushort*)alloc((size_t)FEAT * FEAT * 2);
    ushort* w1rb   = (ushort*)alloc((size_t)FEAT * FEAT * 2);
    ushort* w2lb   = (ushort*)alloc((size_t)FEAT * FEAT * 2);
    ushort* w2rb   = (ushort*)alloc((size_t)FEAT * FEAT * 2);
    ushort* h2b = xb;  // xb dead after layer-1 GEMM; reuse for h2

    hipMemsetAsync(cnt, 0, (size_t)M * 4, stream);
    hipMemsetAsync(pooled, 0, (size_t)GR * FEAT * 4, stream);

    int NB = (M + 1023) / 1024;
    k_cast <<<(M * FEAT / 4 + 255) / 256, 256, 0, stream>>>(x, xb, M * FEAT / 4);
    k_castw<<<64, 256, 0, stream>>>(W1l, W1r, W2l, W2r, w1lb, w1rb, w2lb, w2rb);
    k_count<<<(E + 255) / 256, 256, 0, stream>>>(dst, cnt, E);
    k_scan1<<<NB, 256, 0, stream>>>(cnt, rowp, bsum, M);
    k_scan2<<<1, 128, 0, stream>>>(bsum, rowp, NB, M);
    k_scan3<<<NB, 256, 0, stream>>>(rowp, cur, bsum, M);
    k_fill <<<(E + 255) / 256, 256, 0, stream>>>(src, dst, cur, csr, E);
    k_agg  <<<(M + 3) / 4, 256, 0, stream>>>(xb, rowp, csr, aggb, M);
    k_gemm <<<(M + 63) / 64, 256, 0, stream>>>(aggb, xb, w1lb, w1rb, b1l, h1b, M);
    k_agg  <<<(M + 3) / 4, 256, 0, stream>>>(h1b, rowp, csr, aggb, M);
    k_gemm <<<(M + 63) / 64, 256, 0, stream>>>(aggb, h1b, w2lb, w2rb, b2l, h2b, M);
    k_pool <<<(M + 31) / 32, 256, 0, stream>>>(h2b, batch, pooled, M);
    k_final<<<1, 512, 0, stream>>>(pooled, batch, embed, Wlin, blin, out, M);
}

// Round 5
// 328.479 us; speedup vs baseline: 1.5131x; 1.1743x over previous
//
#include <hip/hip_runtime.h>
#include <stdint.h>

#define FEAT   128
#define GR     64
#define LDA    136   // 128 + 8 bf16 pad
#define NBUCK  256
#define BSHIFT 9     // 512 nodes per bucket

typedef __attribute__((ext_vector_type(8))) short bf8_t;
typedef __attribute__((ext_vector_type(4))) float f4_t;

__device__ inline float bf2f(ushort h){
    union { uint u; float f; } v; v.u = ((uint)h) << 16; return v.f;
}
__device__ inline ushort f2bf(float f){
    union { float f; uint u; } v; v.f = f;
    uint r = (v.u + 0x7FFFu + ((v.u >> 16) & 1u)) >> 16;   // RNE
    return (ushort)r;
}

// ---------------- cast fp32 -> bf16 (node features) ----------------
__global__ void k_cast(const float* __restrict__ x, ushort* __restrict__ xb, int n4){
    int i = blockIdx.x * blockDim.x + threadIdx.x;
    if (i >= n4) return;
    float4 v = ((const float4*)x)[i];
    ushort4 o; o.x = f2bf(v.x); o.y = f2bf(v.y); o.z = f2bf(v.z); o.w = f2bf(v.w);
    ((ushort4*)xb)[i] = o;
}

// cast all four 128x128 weight matrices in one launch
__global__ void k_castw(const float* __restrict__ a0, const float* __restrict__ a1,
                        const float* __restrict__ a2, const float* __restrict__ a3,
                        ushort* __restrict__ o0, ushort* __restrict__ o1,
                        ushort* __restrict__ o2, ushort* __restrict__ o3){
    int i = blockIdx.x * blockDim.x + threadIdx.x;   // 0..16383 float4s
    int sel = i >> 12, j = i & 4095;
    const float* s = sel == 0 ? a0 : sel == 1 ? a1 : sel == 2 ? a2 : a3;
    ushort*      d = sel == 0 ? o0 : sel == 1 ? o1 : sel == 2 ? o2 : o3;
    float4 v = ((const float4*)s)[j];
    ushort4 o; o.x = f2bf(v.x); o.y = f2bf(v.y); o.z = f2bf(v.z); o.w = f2bf(v.w);
    ((ushort4*)d)[j] = o;
}

// ================= CSR build via bucket counting-sort =================
// Stage 1: per-block LDS histogram of dst buckets, one global atomic/bucket/block
__global__ void k_hist(const int* __restrict__ dst, int* __restrict__ bcnt, int E){
    __shared__ int h[NBUCK];
    h[threadIdx.x] = 0;
    __syncthreads();
    int base = blockIdx.x * 4096 + threadIdx.x;
    #pragma unroll
    for (int k = 0; k < 16; k++){
        int e = base + k * 256;
        if (e < E) atomicAdd(&h[dst[e] >> BSHIFT], 1);
    }
    __syncthreads();
    int c = h[threadIdx.x];
    if (c) atomicAdd(&bcnt[threadIdx.x], c);
}

// Stage 2: exclusive scan of 256 bucket counts; init bucket cursors; rowp[M]=E
__global__ void k_bscan(const int* __restrict__ bcnt, int* __restrict__ bbase,
                        int* __restrict__ bpos, int* __restrict__ rowp, int E, int M){
    __shared__ int sd[NBUCK];
    int t = threadIdx.x;
    int v = bcnt[t];
    sd[t] = v; __syncthreads();
    for (int off = 1; off < NBUCK; off <<= 1){
        int x = (t >= off) ? sd[t - off] : 0;
        __syncthreads();
        sd[t] += x;
        __syncthreads();
    }
    int ex = sd[t] - v;
    bbase[t] = ex;
    bpos[t]  = ex;
    if (t == NBUCK - 1){ bbase[NBUCK] = sd[t]; rowp[M] = E; }
}

// Stage 3: scatter edges into bucket-sorted pair array (dense per-block segments)
__global__ __launch_bounds__(256) void k_bucket(const int* __restrict__ src,
                                                const int* __restrict__ dst,
                                                int* __restrict__ bpos,
                                                int2* __restrict__ bp, int E){
    __shared__ int h[NBUCK];
    __shared__ int bb[NBUCK];
    int t = threadIdx.x;
    h[t] = 0;
    __syncthreads();
    int base = blockIdx.x * 4096 + t;
    int bk[16], sv[16], dv[16];
    #pragma unroll
    for (int k = 0; k < 16; k++){
        int e = base + k * 256;
        if (e < E){
            dv[k] = dst[e]; sv[k] = src[e];
            bk[k] = dv[k] >> BSHIFT;
            atomicAdd(&h[bk[k]], 1);
        } else bk[k] = -1;
    }
    __syncthreads();
    int c = h[t];
    bb[t] = c ? atomicAdd(&bpos[t], c) : 0;
    __syncthreads();
    h[t] = 0;
    __syncthreads();
    #pragma unroll
    for (int k = 0; k < 16; k++){
        if (bk[k] >= 0){
            int r = atomicAdd(&h[bk[k]], 1);
            bp[bb[bk[k]] + r] = make_int2(sv[k], dv[k]);
        }
    }
}

// Stage 4: per-bucket CSR finalize — per-node count, LDS scan, local scatter
__global__ __launch_bounds__(512) void k_csr(const int2* __restrict__ bp,
                                             const int* __restrict__ bbase,
                                             int* __restrict__ rowp,
                                             int* __restrict__ csr, int M){
    __shared__ int cnt[512];
    __shared__ int sd[512];
    int b = blockIdx.x, t = threadIdx.x;
    int nbase = b << BSHIFT;
    int nnodes = min(512, M - nbase);
    int e0 = bbase[b], e1 = bbase[b + 1];
    cnt[t] = 0;
    __syncthreads();
    for (int e = e0 + t; e < e1; e += 512)
        atomicAdd(&cnt[bp[e].y - nbase], 1);
    __syncthreads();
    int v = cnt[t];
    sd[t] = v; __syncthreads();
    for (int off = 1; off < 512; off <<= 1){
        int x = (t >= off) ? sd[t - off] : 0;
        __syncthreads();
        sd[t] += x;
        __syncthreads();
    }
    int ex = sd[t] - v;
    if (t < nnodes) rowp[nbase + t] = e0 + ex;
    cnt[t] = ex;     // running cursor
    __syncthreads();
    for (int e = e0 + t; e < e1; e += 512){
        int2 pr = bp[e];
        int r = atomicAdd(&cnt[pr.y - nbase], 1);
        csr[e0 + r] = pr.x;
    }
}

// ---------------- mean aggregation (gather over CSR), 8-deep MLP unroll ----------------
__global__ void k_agg(const ushort* __restrict__ srcf, const int* __restrict__ rowp,
                      const int* __restrict__ csr, ushort* __restrict__ aggb, int M){
    int node = blockIdx.x * 4 + (threadIdx.x >> 6);
    int f2 = threadIdx.x & 63;
    if (node >= M) return;
    int s = rowp[node], e = rowp[node + 1];
    float a0 = 0.f, a1 = 0.f, b0 = 0.f, b1 = 0.f;
    float c0 = 0.f, c1 = 0.f, d0 = 0.f, d1 = 0.f;
    float e0 = 0.f, e1 = 0.f, g0 = 0.f, g1 = 0.f;
    float p0 = 0.f, p1 = 0.f, q0 = 0.f, q1 = 0.f;
    int i = s;
    for (; i + 8 <= e; i += 8){
        int sn0 = csr[i],     sn1 = csr[i + 1], sn2 = csr[i + 2], sn3 = csr[i + 3];
        int sn4 = csr[i + 4], sn5 = csr[i + 5], sn6 = csr[i + 6], sn7 = csr[i + 7];
        uint v0 = *(const uint*)(srcf + (size_t)sn0 * FEAT + f2 * 2);
        uint v1 = *(const uint*)(srcf + (size_t)sn1 * FEAT + f2 * 2);
        uint v2 = *(const uint*)(srcf + (size_t)sn2 * FEAT + f2 * 2);
        uint v3 = *(const uint*)(srcf + (size_t)sn3 * FEAT + f2 * 2);
        uint v4 = *(const uint*)(srcf + (size_t)sn4 * FEAT + f2 * 2);
        uint v5 = *(const uint*)(srcf + (size_t)sn5 * FEAT + f2 * 2);
        uint v6 = *(const uint*)(srcf + (size_t)sn6 * FEAT + f2 * 2);
        uint v7 = *(const uint*)(srcf + (size_t)sn7 * FEAT + f2 * 2);
        a0 += bf2f((ushort)(v0 & 0xffffu)); a1 += bf2f((ushort)(v0 >> 16));
        b0 += bf2f((ushort)(v1 & 0xffffu)); b1 += bf2f((ushort)(v1 >> 16));
        c0 += bf2f((ushort)(v2 & 0xffffu)); c1 += bf2f((ushort)(v2 >> 16));
        d0 += bf2f((ushort)(v3 & 0xffffu)); d1 += bf2f((ushort)(v3 >> 16));
        e0 += bf2f((ushort)(v4 & 0xffffu)); e1 += bf2f((ushort)(v4 >> 16));
        g0 += bf2f((ushort)(v5 & 0xffffu)); g1 += bf2f((ushort)(v5 >> 16));
        p0 += bf2f((ushort)(v6 & 0xffffu)); p1 += bf2f((ushort)(v6 >> 16));
        q0 += bf2f((ushort)(v7 & 0xffffu)); q1 += bf2f((ushort)(v7 >> 16));
    }
    for (; i + 2 <= e; i += 2){
        int sn0 = csr[i], sn1 = csr[i + 1];
        uint v0 = *(const uint*)(srcf + (size_t)sn0 * FEAT + f2 * 2);
        uint v1 = *(const uint*)(srcf + (size_t)sn1 * FEAT + f2 * 2);
        a0 += bf2f((ushort)(v0 & 0xffffu)); a1 += bf2f((ushort)(v0 >> 16));
        b0 += bf2f((ushort)(v1 & 0xffffu)); b1 += bf2f((ushort)(v1 >> 16));
    }
    if (i < e){
        int sn = csr[i];
        uint v = *(const uint*)(srcf + (size_t)sn * FEAT + f2 * 2);
        a0 += bf2f((ushort)(v & 0xffffu)); a1 += bf2f((ushort)(v >> 16));
    }
    float s0 = ((a0 + b0) + (c0 + d0)) + ((e0 + g0) + (p0 + q0));
    float s1 = ((a1 + b1) + (c1 + d1)) + ((e1 + g1) + (p1 + q1));
    float inv = (e > s) ? 1.0f / (float)(e - s) : 0.f;  // count clamped to 1
    uint o = ((uint)f2bf(s1 * inv) << 16) | (uint)f2bf(s0 * inv);
    *(uint*)(aggb + (size_t)node * FEAT + f2 * 2) = o;
}

// ---------------- fused SAGE linear: H = relu(AGG@Wl^T + b + A@Wr^T) ----------------
__global__ __launch_bounds__(256) void k_gemm(
    const ushort* __restrict__ Aagg, const ushort* __restrict__ Aself,
    const ushort* __restrict__ Wl, const ushort* __restrict__ Wr,
    const float* __restrict__ bias, ushort* __restrict__ Hout, int M)
{
    __shared__ ushort As[64 * LDA];
    __shared__ ushort Bs[128 * LDA];
    const int tid  = threadIdx.x;
    const int lane = tid & 63;
    const int wave = tid >> 6;
    const int l15  = lane & 15;
    const int quad = lane >> 4;
    const int m0   = blockIdx.x * 64;

    f4_t acc[8];
    #pragma unroll
    for (int i = 0; i < 8; i++) acc[i] = (f4_t){0.f, 0.f, 0.f, 0.f};

    #pragma unroll
    for (int pass = 0; pass < 2; pass++){
        const ushort* Ap = pass ? Aself : Aagg;
        const ushort* Wp = pass ? Wr    : Wl;
        #pragma unroll
        for (int it = 0; it < 4; it++){
            int idx = (it * 256 + tid) * 8;
            int r = idx >> 7, c = idx & 127;
            int4 v = {0, 0, 0, 0};
            if (m0 + r < M) v = *(const int4*)(Ap + (size_t)(m0 + r) * FEAT + c);
            *(int4*)(&As[r * LDA + c]) = v;
        }
        #pragma unroll
        for (int it = 0; it < 8; it++){
            int idx = (it * 256 + tid) * 8;
            int r = idx >> 7, c = idx & 127;
            *(int4*)(&Bs[r * LDA + c]) = *(const int4*)(Wp + idx);
        }
        __syncthreads();
        const ushort* arow = &As[(wave * 16 + l15) * LDA + quad * 8];
        const ushort* brow = &Bs[l15 * LDA + quad * 8];
        #pragma unroll
        for (int nt = 0; nt < 8; nt++){
            #pragma unroll
            for (int ks = 0; ks < 4; ks++){
                bf8_t a = *(const bf8_t*)(arow + ks * 32);
                bf8_t b = *(const bf8_t*)(brow + nt * 16 * LDA + ks * 32);
                acc[nt] = __builtin_amdgcn_mfma_f32_16x16x32_bf16(a, b, acc[nt], 0, 0, 0);
            }
        }
        __syncthreads();
    }
    #pragma unroll
    for (int nt = 0; nt < 8; nt++){
        int col = nt * 16 + l15;
        float bcol = bias[col];
        #pragma unroll
        for (int reg = 0; reg < 4; reg++){
            int gm = m0 + wave * 16 + quad * 4 + reg;
            if (gm < M){
                float v = acc[nt][reg] + bcol;
                v = v > 0.f ? v : 0.f;
                Hout[(size_t)gm * FEAT + col] = f2bf(v);
            }
        }
    }
}

// ---------------- pooling: sorted batch; 16 nodes/thread, 4-wide unroll ----------------
__global__ void k_pool(const ushort* __restrict__ h, const int* __restrict__ batch,
                       float* __restrict__ pooled, int M){
    int f   = threadIdx.x & 127;
    int sub = threadIdx.x >> 7;
    int n0  = (blockIdx.x * 2 + sub) * 16;
    if (n0 >= M) return;
    int n1 = min(n0 + 16, M);
    int g = batch[n0];
    float s = 0.f;
    int n = n0;
    for (; n + 4 <= n1; n += 4){
        int g0 = batch[n], g1 = batch[n + 1], g2 = batch[n + 2], g3 = batch[n + 3];
        float v0 = bf2f(h[(size_t)n * FEAT + f]);
        float v1 = bf2f(h[(size_t)(n + 1) * FEAT + f]);
        float v2 = bf2f(h[(size_t)(n + 2) * FEAT + f]);
        float v3 = bf2f(h[(size_t)(n + 3) * FEAT + f]);
        if (g0 != g){ atomicAdd(&pooled[g * FEAT + f], s); s = 0.f; g = g0; } s += v0;
        if (g1 != g){ atomicAdd(&pooled[g * FEAT + f], s); s = 0.f; g = g1; } s += v1;
        if (g2 != g){ atomicAdd(&pooled[g * FEAT + f], s); s = 0.f; g = g2; } s += v2;
        if (g3 != g){ atomicAdd(&pooled[g * FEAT + f], s); s = 0.f; g = g3; } s += v3;
    }
    for (; n < n1; n++){
        int gn = batch[n];
        if (gn != g){ atomicAdd(&pooled[g * FEAT + f], s); s = 0.f; g = gn; }
        s += bf2f(h[(size_t)n * FEAT + f]);
    }
    atomicAdd(&pooled[g * FEAT + f], s);
}

// ---------------- final linear over [pooled/cnt | embed] ----------------
__global__ void k_final(const float* __restrict__ pooled, const int* __restrict__ batch,
                        const float* __restrict__ embed, const float* __restrict__ Wlin,
                        const float* __restrict__ blin, float* __restrict__ out, int M){
    int t = threadIdx.x;
    if (t >= GR * 8) return;
    int g = t >> 3, o = t & 7;
    int lo = 0, hi = M;
    while (lo < hi){ int mid = (lo + hi) >> 1; if (batch[mid] < g) lo = mid + 1; else hi = mid; }
    int s0 = lo;
    lo = s0; hi = M;
    while (lo < hi){ int mid = (lo + hi) >> 1; if (batch[mid] < g + 1) lo = mid + 1; else hi = mid; }
    int c = lo - s0;
    float inv = (c > 0) ? 1.0f / (float)c : 0.f;
    float acc = blin[o];
    const float* wr = Wlin + o * (FEAT + GR);
    for (int k = 0; k < FEAT; k++) acc += pooled[g * FEAT + k] * inv * wr[k];
    for (int k = 0; k < GR; k++)   acc += embed[g * GR + k] * wr[FEAT + k];
    out[g * 8 + o] = acc;
}

extern "C" void kernel_launch(void* const* d_in, const int* in_sizes, int n_in,
                              void* d_out, int out_size, void* d_ws, size_t ws_size,
                              hipStream_t stream)
{
    const float* x     = (const float*)d_in[0];
    const int*   eidx  = (const int*)d_in[1];
    const int*   batch = (const int*)d_in[2];
    const float* embed = (const float*)d_in[3];
    const float* W1l   = (const float*)d_in[4];
    const float* b1l   = (const float*)d_in[5];
    const float* W1r   = (const float*)d_in[6];
    const float* W2l   = (const float*)d_in[7];
    const float* b2l   = (const float*)d_in[8];
    const float* W2r   = (const float*)d_in[9];
    const float* Wlin  = (const float*)d_in[10];
    const float* blin  = (const float*)d_in[11];
    float* out = (float*)d_out;

    const int M = in_sizes[0] / FEAT;   // 100000
    const int E = in_sizes[1] / 2;      // 800000
    const int* src = eidx;
    const int* dst = eidx + E;

    char* w = (char*)d_ws;
    size_t off = 0;
    auto alloc = [&](size_t sz){ void* p = w + off; off = (off + sz + 255) & ~(size_t)255; return p; };
    ushort* xb     = (ushort*)alloc((size_t)M * FEAT * 2);
    ushort* aggb   = (ushort*)alloc((size_t)M * FEAT * 2);
    ushort* h1b    = (ushort*)alloc((size_t)M * FEAT * 2);
    int*    rowp   = (int*)alloc((size_t)(M + 1) * 4);
    int*    csr    = (int*)alloc((size_t)E * 4);
    int*    bcnt   = (int*)alloc(NBUCK * 4);
    int*    bbase  = (int*)alloc((NBUCK + 1) * 4);
    int*    bpos   = (int*)alloc(NBUCK * 4);
    float*  pooled = (float*)alloc((size_t)GR * FEAT * 4);
    ushort* w1lb   = (ushort*)alloc((size_t)FEAT * FEAT * 2);
    ushort* w1rb   = (ushort*)alloc((size_t)FEAT * FEAT * 2);
    ushort* w2lb   = (ushort*)alloc((size_t)FEAT * FEAT * 2);
    ushort* w2rb   = (ushort*)alloc((size_t)FEAT * FEAT * 2);
    int2*   bp     = (int2*)aggb;   // bucket-sorted pairs; dead before aggb first written
    ushort* h2b    = xb;            // xb dead after layer-1 GEMM; reuse for h2

    hipMemsetAsync(bcnt, 0, NBUCK * 4, stream);
    hipMemsetAsync(pooled, 0, (size_t)GR * FEAT * 4, stream);

    const int nb   = (M + 511) >> BSHIFT;       // buckets actually populated
    const int ebk  = (E + 4095) / 4096;         // edge-chunk blocks
    k_cast  <<<(M * FEAT / 4 + 255) / 256, 256, 0, stream>>>(x, xb, M * FEAT / 4);
    k_castw <<<64, 256, 0, stream>>>(W1l, W1r, W2l, W2r, w1lb, w1rb, w2lb, w2rb);
    k_hist  <<<ebk, 256, 0, stream>>>(dst, bcnt, E);
    k_bscan <<<1, NBUCK, 0, stream>>>(bcnt, bbase, bpos, rowp, E, M);
    k_bucket<<<ebk, 256, 0, stream>>>(src, dst, bpos, bp, E);
    k_csr   <<<nb, 512, 0, stream>>>(bp, bbase, rowp, csr, M);
    k_agg   <<<(M + 3) / 4, 256, 0, stream>>>(xb, rowp, csr, aggb, M);
    k_gemm  <<<(M + 63) / 64, 256, 0, stream>>>(aggb, xb, w1lb, w1rb, b1l, h1b, M);
    k_agg   <<<(M + 3) / 4, 256, 0, stream>>>(h1b, rowp, csr, aggb, M);
    k_gemm  <<<(M + 63) / 64, 256, 0, stream>>>(aggb, h1b, w2lb, w2rb, b2l, h2b, M);
    k_pool  <<<(M + 31) / 32, 256, 0, stream>>>(h2b, batch, pooled, M);
    k_final <<<1, 512, 0, stream>>>(pooled, batch, embed, Wlin, blin, out, M);
}

// Round 6
// 327.141 us; speedup vs baseline: 1.5193x; 1.0041x over previous
//
#include <hip/hip_runtime.h>
#include <stdint.h>

#define FEAT   128
#define GR     64
#define LDA    136   // 128 + 8 bf16 pad
#define NBUCK  256
#define BSHIFT 9     // 512 nodes per bucket

typedef __attribute__((ext_vector_type(8))) short bf8_t;
typedef __attribute__((ext_vector_type(4))) float f4_t;

__device__ inline float bf2f(ushort h){
    union { uint u; float f; } v; v.u = ((uint)h) << 16; return v.f;
}
__device__ inline float bf2f_lo(uint u){   // low bf16 of packed pair -> float
    union { uint u; float f; } v; v.u = u << 16; return v.f;
}
__device__ inline float bf2f_hi(uint u){   // high bf16 of packed pair -> float
    union { uint u; float f; } v; v.u = u & 0xffff0000u; return v.f;
}
__device__ inline ushort f2bf(float f){
    union { float f; uint u; } v; v.f = f;
    uint r = (v.u + 0x7FFFu + ((v.u >> 16) & 1u)) >> 16;   // RNE
    return (ushort)r;
}

// ---------------- cast fp32 -> bf16 (node features) ----------------
__global__ void k_cast(const float* __restrict__ x, ushort* __restrict__ xb, int n4){
    int i = blockIdx.x * blockDim.x + threadIdx.x;
    if (i >= n4) return;
    float4 v = ((const float4*)x)[i];
    ushort4 o; o.x = f2bf(v.x); o.y = f2bf(v.y); o.z = f2bf(v.z); o.w = f2bf(v.w);
    ((ushort4*)xb)[i] = o;
}

// cast all four 128x128 weight matrices in one launch
__global__ void k_castw(const float* __restrict__ a0, const float* __restrict__ a1,
                        const float* __restrict__ a2, const float* __restrict__ a3,
                        ushort* __restrict__ o0, ushort* __restrict__ o1,
                        ushort* __restrict__ o2, ushort* __restrict__ o3){
    int i = blockIdx.x * blockDim.x + threadIdx.x;   // 0..16383 float4s
    int sel = i >> 12, j = i & 4095;
    const float* s = sel == 0 ? a0 : sel == 1 ? a1 : sel == 2 ? a2 : a3;
    ushort*      d = sel == 0 ? o0 : sel == 1 ? o1 : sel == 2 ? o2 : o3;
    float4 v = ((const float4*)s)[j];
    ushort4 o; o.x = f2bf(v.x); o.y = f2bf(v.y); o.z = f2bf(v.z); o.w = f2bf(v.w);
    ((ushort4*)d)[j] = o;
}

// ================= CSR build via bucket counting-sort =================
__global__ void k_hist(const int* __restrict__ dst, int* __restrict__ bcnt, int E){
    __shared__ int h[NBUCK];
    h[threadIdx.x] = 0;
    __syncthreads();
    int base = blockIdx.x * 4096 + threadIdx.x;
    #pragma unroll
    for (int k = 0; k < 16; k++){
        int e = base + k * 256;
        if (e < E) atomicAdd(&h[dst[e] >> BSHIFT], 1);
    }
    __syncthreads();
    int c = h[threadIdx.x];
    if (c) atomicAdd(&bcnt[threadIdx.x], c);
}

__global__ void k_bscan(const int* __restrict__ bcnt, int* __restrict__ bbase,
                        int* __restrict__ bpos, int* __restrict__ rowp,
                        int* __restrict__ csr, int E, int M){
    __shared__ int sd[NBUCK];
    int t = threadIdx.x;
    int v = bcnt[t];
    sd[t] = v; __syncthreads();
    for (int off = 1; off < NBUCK; off <<= 1){
        int x = (t >= off) ? sd[t - off] : 0;
        __syncthreads();
        sd[t] += x;
        __syncthreads();
    }
    int ex = sd[t] - v;
    bbase[t] = ex;
    bpos[t]  = ex;
    if (t < 8) csr[E + t] = 0;                 // zero the read-ahead pad
    if (t == NBUCK - 1){ bbase[NBUCK] = sd[t]; rowp[M] = E; }
}

__global__ __launch_bounds__(256) void k_bucket(const int* __restrict__ src,
                                                const int* __restrict__ dst,
                                                int* __restrict__ bpos,
                                                int2* __restrict__ bp, int E){
    __shared__ int h[NBUCK];
    __shared__ int bb[NBUCK];
    int t = threadIdx.x;
    h[t] = 0;
    __syncthreads();
    int base = blockIdx.x * 4096 + t;
    int bk[16], sv[16], dv[16];
    #pragma unroll
    for (int k = 0; k < 16; k++){
        int e = base + k * 256;
        if (e < E){
            dv[k] = dst[e]; sv[k] = src[e];
            bk[k] = dv[k] >> BSHIFT;
            atomicAdd(&h[bk[k]], 1);
        } else bk[k] = -1;
    }
    __syncthreads();
    int c = h[t];
    bb[t] = c ? atomicAdd(&bpos[t], c) : 0;
    __syncthreads();
    h[t] = 0;
    __syncthreads();
    #pragma unroll
    for (int k = 0; k < 16; k++){
        if (bk[k] >= 0){
            int r = atomicAdd(&h[bk[k]], 1);
            bp[bb[bk[k]] + r] = make_int2(sv[k], dv[k]);
        }
    }
}

__global__ __launch_bounds__(512) void k_csr(const int2* __restrict__ bp,
                                             const int* __restrict__ bbase,
                                             int* __restrict__ rowp,
                                             int* __restrict__ csr, int M){
    __shared__ int cnt[512];
    __shared__ int sd[512];
    int b = blockIdx.x, t = threadIdx.x;
    int nbase = b << BSHIFT;
    int nnodes = min(512, M - nbase);
    int e0 = bbase[b], e1 = bbase[b + 1];
    cnt[t] = 0;
    __syncthreads();
    for (int e = e0 + t; e < e1; e += 512)
        atomicAdd(&cnt[bp[e].y - nbase], 1);
    __syncthreads();
    int v = cnt[t];
    sd[t] = v; __syncthreads();
    for (int off = 1; off < 512; off <<= 1){
        int x = (t >= off) ? sd[t - off] : 0;
        __syncthreads();
        sd[t] += x;
        __syncthreads();
    }
    int ex = sd[t] - v;
    if (t < nnodes) rowp[nbase + t] = e0 + ex;
    cnt[t] = ex;     // running cursor
    __syncthreads();
    for (int e = e0 + t; e < e1; e += 512){
        int2 pr = bp[e];
        int r = atomicAdd(&cnt[pr.y - nbase], 1);
        csr[e0 + r] = pr.x;
    }
}

// ---------------- mean aggregation: batched index loads + 32-bit gather addressing ----
// 64 lanes per node (2 bf16 feats each), 4 nodes per 256-thr block.
// csr indices fetched 8-at-a-time (two dwordx4 broadcasts); gather address is
// a single 32-bit byte offset (sn<<8) off an SGPR base, killing 64-bit addr math.
__global__ void k_agg(const ushort* __restrict__ srcf, const int* __restrict__ rowp,
                      const int* __restrict__ csr, ushort* __restrict__ aggb, int M){
    int node = blockIdx.x * 4 + (threadIdx.x >> 6);
    int lane = threadIdx.x & 63;
    if (node >= M) return;
    int s = rowp[node], e = rowp[node + 1];
    const char* base = (const char*)srcf + (uint)lane * 4u;  // this lane's 2 feats
    float a0 = 0.f, a1 = 0.f, b0 = 0.f, b1 = 0.f;
    float c0 = 0.f, c1 = 0.f, d0 = 0.f, d1 = 0.f;
    float e0 = 0.f, e1 = 0.f, g0 = 0.f, g1 = 0.f;
    float p0 = 0.f, p1 = 0.f, q0 = 0.f, q1 = 0.f;
    int i = s;
    for (; i + 8 <= e; i += 8){
        int idx[8];
        __builtin_memcpy(idx, csr + i, 32);    // two dwordx4 broadcasts
        uint v0 = *(const uint*)(base + ((uint)idx[0] << 8));
        uint v1 = *(const uint*)(base + ((uint)idx[1] << 8));
        uint v2 = *(const uint*)(base + ((uint)idx[2] << 8));
        uint v3 = *(const uint*)(base + ((uint)idx[3] << 8));
        uint v4 = *(const uint*)(base + ((uint)idx[4] << 8));
        uint v5 = *(const uint*)(base + ((uint)idx[5] << 8));
        uint v6 = *(const uint*)(base + ((uint)idx[6] << 8));
        uint v7 = *(const uint*)(base + ((uint)idx[7] << 8));
        a0 += bf2f_lo(v0); a1 += bf2f_hi(v0);
        b0 += bf2f_lo(v1); b1 += bf2f_hi(v1);
        c0 += bf2f_lo(v2); c1 += bf2f_hi(v2);
        d0 += bf2f_lo(v3); d1 += bf2f_hi(v3);
        e0 += bf2f_lo(v4); e1 += bf2f_hi(v4);
        g0 += bf2f_lo(v5); g1 += bf2f_hi(v5);
        p0 += bf2f_lo(v6); p1 += bf2f_hi(v6);
        q0 += bf2f_lo(v7); q1 += bf2f_hi(v7);
    }
    if (i + 4 <= e){
        int idx[4];
        __builtin_memcpy(idx, csr + i, 16);
        uint v0 = *(const uint*)(base + ((uint)idx[0] << 8));
        uint v1 = *(const uint*)(base + ((uint)idx[1] << 8));
        uint v2 = *(const uint*)(base + ((uint)idx[2] << 8));
        uint v3 = *(const uint*)(base + ((uint)idx[3] << 8));
        a0 += bf2f_lo(v0); a1 += bf2f_hi(v0);
        b0 += bf2f_lo(v1); b1 += bf2f_hi(v1);
        c0 += bf2f_lo(v2); c1 += bf2f_hi(v2);
        d0 += bf2f_lo(v3); d1 += bf2f_hi(v3);
        i += 4;
    }
    for (; i < e; i++){
        uint v = *(const uint*)(base + ((uint)csr[i] << 8));
        a0 += bf2f_lo(v); a1 += bf2f_hi(v);
    }
    float s0 = ((a0 + b0) + (c0 + d0)) + ((e0 + g0) + (p0 + q0));
    float s1 = ((a1 + b1) + (c1 + d1)) + ((e1 + g1) + (p1 + q1));
    float inv = (e > s) ? 1.0f / (float)(e - s) : 0.f;  // count clamped to 1
    uint o = ((uint)f2bf(s1 * inv) << 16) | (uint)f2bf(s0 * inv);
    *(uint*)(aggb + (size_t)node * FEAT + lane * 2) = o;
}

// ---------------- fused SAGE linear: H = relu(AGG@Wl^T + b + A@Wr^T) ----------------
__global__ __launch_bounds__(256) void k_gemm(
    const ushort* __restrict__ Aagg, const ushort* __restrict__ Aself,
    const ushort* __restrict__ Wl, const ushort* __restrict__ Wr,
    const float* __restrict__ bias, ushort* __restrict__ Hout, int M)
{
    __shared__ ushort As[64 * LDA];
    __shared__ ushort Bs[128 * LDA];
    const int tid  = threadIdx.x;
    const int lane = tid & 63;
    const int wave = tid >> 6;
    const int l15  = lane & 15;
    const int quad = lane >> 4;
    const int m0   = blockIdx.x * 64;

    f4_t acc[8];
    #pragma unroll
    for (int i = 0; i < 8; i++) acc[i] = (f4_t){0.f, 0.f, 0.f, 0.f};

    #pragma unroll
    for (int pass = 0; pass < 2; pass++){
        const ushort* Ap = pass ? Aself : Aagg;
        const ushort* Wp = pass ? Wr    : Wl;
        #pragma unroll
        for (int it = 0; it < 4; it++){
            int idx = (it * 256 + tid) * 8;
            int r = idx >> 7, c = idx & 127;
            int4 v = {0, 0, 0, 0};
            if (m0 + r < M) v = *(const int4*)(Ap + (size_t)(m0 + r) * FEAT + c);
            *(int4*)(&As[r * LDA + c]) = v;
        }
        #pragma unroll
        for (int it = 0; it < 8; it++){
            int idx = (it * 256 + tid) * 8;
            int r = idx >> 7, c = idx & 127;
            *(int4*)(&Bs[r * LDA + c]) = *(const int4*)(Wp + idx);
        }
        __syncthreads();
        const ushort* arow = &As[(wave * 16 + l15) * LDA + quad * 8];
        const ushort* brow = &Bs[l15 * LDA + quad * 8];
        #pragma unroll
        for (int nt = 0; nt < 8; nt++){
            #pragma unroll
            for (int ks = 0; ks < 4; ks++){
                bf8_t a = *(const bf8_t*)(arow + ks * 32);
                bf8_t b = *(const bf8_t*)(brow + nt * 16 * LDA + ks * 32);
                acc[nt] = __builtin_amdgcn_mfma_f32_16x16x32_bf16(a, b, acc[nt], 0, 0, 0);
            }
        }
        __syncthreads();
    }
    #pragma unroll
    for (int nt = 0; nt < 8; nt++){
        int col = nt * 16 + l15;
        float bcol = bias[col];
        #pragma unroll
        for (int reg = 0; reg < 4; reg++){
            int gm = m0 + wave * 16 + quad * 4 + reg;
            if (gm < M){
                float v = acc[nt][reg] + bcol;
                v = v > 0.f ? v : 0.f;
                Hout[(size_t)gm * FEAT + col] = f2bf(v);
            }
        }
    }
}

// ---------------- pooling: sorted batch; 16 nodes/thread, 4-wide unroll ----------------
__global__ void k_pool(const ushort* __restrict__ h, const int* __restrict__ batch,
                       float* __restrict__ pooled, int M){
    int f   = threadIdx.x & 127;
    int sub = threadIdx.x >> 7;
    int n0  = (blockIdx.x * 2 + sub) * 16;
    if (n0 >= M) return;
    int n1 = min(n0 + 16, M);
    int g = batch[n0];
    float s = 0.f;
    int n = n0;
    for (; n + 4 <= n1; n += 4){
        int g0 = batch[n], g1 = batch[n + 1], g2 = batch[n + 2], g3 = batch[n + 3];
        float v0 = bf2f(h[(size_t)n * FEAT + f]);
        float v1 = bf2f(h[(size_t)(n + 1) * FEAT + f]);
        float v2 = bf2f(h[(size_t)(n + 2) * FEAT + f]);
        float v3 = bf2f(h[(size_t)(n + 3) * FEAT + f]);
        if (g0 != g){ atomicAdd(&pooled[g * FEAT + f], s); s = 0.f; g = g0; } s += v0;
        if (g1 != g){ atomicAdd(&pooled[g * FEAT + f], s); s = 0.f; g = g1; } s += v1;
        if (g2 != g){ atomicAdd(&pooled[g * FEAT + f], s); s = 0.f; g = g2; } s += v2;
        if (g3 != g){ atomicAdd(&pooled[g * FEAT + f], s); s = 0.f; g = g3; } s += v3;
    }
    for (; n < n1; n++){
        int gn = batch[n];
        if (gn != g){ atomicAdd(&pooled[g * FEAT + f], s); s = 0.f; g = gn; }
        s += bf2f(h[(size_t)n * FEAT + f]);
    }
    atomicAdd(&pooled[g * FEAT + f], s);
}

// ---------------- final linear over [pooled/cnt | embed] ----------------
__global__ void k_final(const float* __restrict__ pooled, const int* __restrict__ batch,
                        const float* __restrict__ embed, const float* __restrict__ Wlin,
                        const float* __restrict__ blin, float* __restrict__ out, int M){
    int t = threadIdx.x;
    if (t >= GR * 8) return;
    int g = t >> 3, o = t & 7;
    int lo = 0, hi = M;
    while (lo < hi){ int mid = (lo + hi) >> 1; if (batch[mid] < g) lo = mid + 1; else hi = mid; }
    int s0 = lo;
    lo = s0; hi = M;
    while (lo < hi){ int mid = (lo + hi) >> 1; if (batch[mid] < g + 1) lo = mid + 1; else hi = mid; }
    int c = lo - s0;
    float inv = (c > 0) ? 1.0f / (float)c : 0.f;
    float acc = blin[o];
    const float* wr = Wlin + o * (FEAT + GR);
    for (int k = 0; k < FEAT; k++) acc += pooled[g * FEAT + k] * inv * wr[k];
    for (int k = 0; k < GR; k++)   acc += embed[g * GR + k] * wr[FEAT + k];
    out[g * 8 + o] = acc;
}

extern "C" void kernel_launch(void* const* d_in, const int* in_sizes, int n_in,
                              void* d_out, int out_size, void* d_ws, size_t ws_size,
                              hipStream_t stream)
{
    const float* x     = (const float*)d_in[0];
    const int*   eidx  = (const int*)d_in[1];
    const int*   batch = (const int*)d_in[2];
    const float* embed = (const float*)d_in[3];
    const float* W1l   = (const float*)d_in[4];
    const float* b1l   = (const float*)d_in[5];
    const float* W1r   = (const float*)d_in[6];
    const float* W2l   = (const float*)d_in[7];
    const float* b2l   = (const float*)d_in[8];
    const float* W2r   = (const float*)d_in[9];
    const float* Wlin  = (const float*)d_in[10];
    const float* blin  = (const float*)d_in[11];
    float* out = (float*)d_out;

    const int M = in_sizes[0] / FEAT;   // 100000
    const int E = in_sizes[1] / 2;      // 800000
    const int* src = eidx;
    const int* dst = eidx + E;

    char* w = (char*)d_ws;
    size_t off = 0;
    auto alloc = [&](size_t sz){ void* p = w + off; off = (off + sz + 255) & ~(size_t)255; return p; };
    ushort* xb     = (ushort*)alloc((size_t)M * FEAT * 2);
    ushort* aggb   = (ushort*)alloc((size_t)M * FEAT * 2);
    ushort* h1b    = (ushort*)alloc((size_t)M * FEAT * 2);
    int*    rowp   = (int*)alloc((size_t)(M + 1) * 4);
    int*    csr    = (int*)alloc((size_t)(E + 8) * 4);   // +8 read-ahead pad
    int*    bcnt   = (int*)alloc(NBUCK * 4);
    int*    bbase  = (int*)alloc((NBUCK + 1) * 4);
    int*    bpos   = (int*)alloc(NBUCK * 4);
    float*  pooled = (float*)alloc((size_t)GR * FEAT * 4);
    ushort* w1lb   = (ushort*)alloc((size_t)FEAT * FEAT * 2);
    ushort* w1rb   = (ushort*)alloc((size_t)FEAT * FEAT * 2);
    ushort* w2lb   = (ushort*)alloc((size_t)FEAT * FEAT * 2);
    ushort* w2rb   = (ushort*)alloc((size_t)FEAT * FEAT * 2);
    int2*   bp     = (int2*)aggb;   // bucket-sorted pairs; dead before aggb first written
    ushort* h2b    = xb;            // xb dead after layer-1 GEMM; reuse for h2

    hipMemsetAsync(bcnt, 0, NBUCK * 4, stream);
    hipMemsetAsync(pooled, 0, (size_t)GR * FEAT * 4, stream);

    const int nb   = (M + 511) >> BSHIFT;       // buckets actually populated
    const int ebk  = (E + 4095) / 4096;         // edge-chunk blocks
    k_cast  <<<(M * FEAT / 4 + 255) / 256, 256, 0, stream>>>(x, xb, M * FEAT / 4);
    k_castw <<<64, 256, 0, stream>>>(W1l, W1r, W2l, W2r, w1lb, w1rb, w2lb, w2rb);
    k_hist  <<<ebk, 256, 0, stream>>>(dst, bcnt, E);
    k_bscan <<<1, NBUCK, 0, stream>>>(bcnt, bbase, bpos, rowp, csr, E, M);
    k_bucket<<<ebk, 256, 0, stream>>>(src, dst, bpos, bp, E);
    k_csr   <<<nb, 512, 0, stream>>>(bp, bbase, rowp, csr, M);
    k_agg   <<<(M + 3) / 4, 256, 0, stream>>>(xb, rowp, csr, aggb, M);
    k_gemm  <<<(M + 63) / 64, 256, 0, stream>>>(aggb, xb, w1lb, w1rb, b1l, h1b, M);
    k_agg   <<<(M + 3) / 4, 256, 0, stream>>>(h1b, rowp, csr, aggb, M);
    k_gemm  <<<(M + 63) / 64, 256, 0, stream>>>(aggb, h1b, w2lb, w2rb, b2l, h2b, M);
    k_pool  <<<(M + 31) / 32, 256, 0, stream>>>(h2b, batch, pooled, M);
    k_final <<<1, 512, 0, stream>>>(pooled, batch, embed, Wlin, blin, out, M);
}